// Round 1
// baseline (350.499 us; speedup 1.0000x reference)
//
#include <hip/hip_runtime.h>

// GCN forward, f32 end-to-end.
// Pipeline:
//  K1 init degrees to 1 (self-loop)
//  K2 edge degree atomics
//  K3 norms + agg1 init with self-loop contribution (norm_src[i]*x[i])
//  K4 feature scatter: agg1[dst] += norm_src[src]*x[src]   (64 lanes/edge)
//  K5 per-node: a = agg1*norm_dst; h = relu(a@W1+b1); z = h@W2;
//     zs[i] = out_acc[i] = norm_src[i]*z
//  K6 scalar scatter: out_acc[dst] += zs[src]
//  K7 out[i] = norm_dst[i]*out_acc[i] + b2

constexpr int D = 64;

__global__ void k_init_deg(float* __restrict__ deg_out,
                           float* __restrict__ deg_in, int n) {
    int i = blockIdx.x * blockDim.x + threadIdx.x;
    if (i < n) { deg_out[i] = 1.0f; deg_in[i] = 1.0f; }
}

__global__ void k_edge_deg(const int* __restrict__ src, const int* __restrict__ dst,
                           float* __restrict__ deg_out, float* __restrict__ deg_in, int e) {
    int i = blockIdx.x * blockDim.x + threadIdx.x;
    if (i < e) {
        atomicAdd(&deg_out[src[i]], 1.0f);
        atomicAdd(&deg_in[dst[i]], 1.0f);
    }
}

__global__ void k_norm_init(const float* __restrict__ x,
                            const float* __restrict__ deg_out,
                            const float* __restrict__ deg_in,
                            float* __restrict__ norm_src, float* __restrict__ norm_dst,
                            float* __restrict__ agg1, int n) {
    int idx = blockIdx.x * blockDim.x + threadIdx.x;
    int i = idx >> 6;
    int d = idx & 63;
    if (i >= n) return;
    float ns = rsqrtf(deg_out[i]);   // deg >= 1 always (self-loop)
    if (d == 0) {
        norm_src[i] = ns;
        norm_dst[i] = rsqrtf(deg_in[i]);
    }
    agg1[i * D + d] = ns * x[i * D + d];   // self-loop contribution
}

// one edge per 64-lane group; lane d handles feature d
__global__ void k_scatter_feat(const int* __restrict__ src, const int* __restrict__ dst,
                               const float* __restrict__ x,
                               const float* __restrict__ norm_src,
                               float* __restrict__ agg1, int e) {
    int idx = blockIdx.x * blockDim.x + threadIdx.x;
    int ei = idx >> 6;
    int d = idx & 63;
    if (ei >= e) return;
    int s = src[ei];
    int t = dst[ei];
    float v = norm_src[s] * x[s * D + d];
    atomicAdd(&agg1[t * D + d], v);
}

// 256 threads = 4 waves; one node per wave. W1/b1/W2 staged in LDS.
__global__ void k_mlp(const float* __restrict__ agg1,
                      const float* __restrict__ norm_src,
                      const float* __restrict__ norm_dst,
                      const float* __restrict__ W1, const float* __restrict__ b1,
                      const float* __restrict__ W2,
                      float* __restrict__ zs, float* __restrict__ out_acc, int n) {
    __shared__ float sW1[D * D];
    __shared__ float sb1[D];
    __shared__ float sW2[D];
    __shared__ float sa[4][D];
    int tid = threadIdx.x;
    for (int k = tid; k < D * D; k += 256) sW1[k] = W1[k];
    if (tid < D) { sb1[tid] = b1[tid]; sW2[tid] = W2[tid]; }
    __syncthreads();

    int wave = tid >> 6;
    int lane = tid & 63;
    int node = blockIdx.x * 4 + wave;
    if (node >= n) return;   // no __syncthreads after this point

    float nd = norm_dst[node];
    sa[wave][lane] = agg1[node * D + lane] * nd;  // same-wave LDS, no barrier needed

    float acc = sb1[lane];
#pragma unroll
    for (int k = 0; k < D; ++k)
        acc += sa[wave][k] * sW1[k * D + lane];   // sa broadcast; sW1 2-way (free)
    float h = fmaxf(acc, 0.0f);

    float zp = h * sW2[lane];
#pragma unroll
    for (int off = 32; off > 0; off >>= 1) zp += __shfl_down(zp, off);

    if (lane == 0) {
        float z = zp * norm_src[node];   // pre-scale for layer-2 aggregation
        zs[node] = z;
        out_acc[node] = z;               // self-loop contribution
    }
}

__global__ void k_scatter_z(const int* __restrict__ src, const int* __restrict__ dst,
                            const float* __restrict__ zs,
                            float* __restrict__ out_acc, int e) {
    int i = blockIdx.x * blockDim.x + threadIdx.x;
    if (i < e) atomicAdd(&out_acc[dst[i]], zs[src[i]]);
}

__global__ void k_final(const float* __restrict__ out_acc,
                        const float* __restrict__ norm_dst,
                        const float* __restrict__ b2,
                        float* __restrict__ out, int n) {
    int i = blockIdx.x * blockDim.x + threadIdx.x;
    if (i < n) out[i] = out_acc[i] * norm_dst[i] + b2[0];
}

extern "C" void kernel_launch(void* const* d_in, const int* in_sizes, int n_in,
                              void* d_out, int out_size, void* d_ws, size_t ws_size,
                              hipStream_t stream) {
    const float* x  = (const float*)d_in[0];
    const int*   ei = (const int*)d_in[1];
    const float* W1 = (const float*)d_in[2];
    const float* b1 = (const float*)d_in[3];
    const float* W2 = (const float*)d_in[4];
    const float* b2 = (const float*)d_in[5];
    float* out = (float*)d_out;

    const int n = in_sizes[0] / D;       // 50000
    const int e = in_sizes[1] / 2;       // 800000
    const int* src = ei;
    const int* dst = ei + e;

    // workspace layout (floats)
    float* ws       = (float*)d_ws;
    float* deg_out  = ws;                // N
    float* deg_in   = ws + (size_t)n;    // N
    float* norm_src = ws + 2 * (size_t)n;
    float* norm_dst = ws + 3 * (size_t)n;
    float* zs       = ws + 4 * (size_t)n;
    float* out_acc  = ws + 5 * (size_t)n;
    float* agg1     = ws + 6 * (size_t)n; // N*64

    const int B = 256;

    k_init_deg<<<(n + B - 1) / B, B, 0, stream>>>(deg_out, deg_in, n);
    k_edge_deg<<<(e + B - 1) / B, B, 0, stream>>>(src, dst, deg_out, deg_in, e);
    k_norm_init<<<((size_t)n * D + B - 1) / B, B, 0, stream>>>(
        x, deg_out, deg_in, norm_src, norm_dst, agg1, n);
    k_scatter_feat<<<((size_t)e * D + B - 1) / B, B, 0, stream>>>(
        src, dst, x, norm_src, agg1, e);
    k_mlp<<<(n + 3) / 4, B, 0, stream>>>(agg1, norm_src, norm_dst, W1, b1, W2,
                                         zs, out_acc, n);
    k_scatter_z<<<(e + B - 1) / B, B, 0, stream>>>(src, dst, zs, out_acc, e);
    k_final<<<(n + B - 1) / B, B, 0, stream>>>(out_acc, norm_dst, b2, out, n);
}

// Round 2
// 279.156 us; speedup vs baseline: 1.2556x; 1.2556x over previous
//
#include <hip/hip_runtime.h>

// GCN forward, f32, CSR-gather formulation (no feature atomics).
// Pipeline:
//  K1 zero in/out degree counters
//  K2 edge histogram (int atomics): cnt_out[src]++, cnt_in[dst]++
//  K3 per-block exclusive scan of cnt_in -> row_ptr (partial) + block sums
//  K4 exclusive scan of block sums (single block, carry loop)
//  K5 finalize: row_ptr += bsum[block], cursor=row_ptr, norms from counts(+1 self loop)
//  K6 bin edges by dst: col[cursor[dst]++] = src
//  K7 fused per-node: agg = norm_dst*(norm_src[i]*x[i] + sum_edges norm_src[s]*x[s]);
//     h = relu(agg@W1+b1); z = h@W2; zs[i] = norm_src[i]*z
//  K8 out[i] = norm_dst[i]*(zs[i] + sum_edges zs[col]) + b2

constexpr int D = 64;

__global__ void k_zero(int* __restrict__ cnt_out, int* __restrict__ cnt_in, int n) {
    int i = blockIdx.x * blockDim.x + threadIdx.x;
    if (i < n) { cnt_out[i] = 0; cnt_in[i] = 0; }
}

__global__ void k_hist(const int* __restrict__ src, const int* __restrict__ dst,
                       int* __restrict__ cnt_out, int* __restrict__ cnt_in, int e) {
    int i = blockIdx.x * blockDim.x + threadIdx.x;
    if (i < e) {
        atomicAdd(&cnt_out[src[i]], 1);
        atomicAdd(&cnt_in[dst[i]], 1);
    }
}

// per-block exclusive scan (256 elems/block); row_ptr gets within-block exclusive,
// bsum[block] gets block total
__global__ void k_scan_block(const int* __restrict__ cnt_in, int* __restrict__ row_ptr,
                             int* __restrict__ bsum, int n) {
    __shared__ int s[256];
    int tid = threadIdx.x;
    int i = blockIdx.x * 256 + tid;
    int v = (i < n) ? cnt_in[i] : 0;
    s[tid] = v;
    __syncthreads();
#pragma unroll
    for (int off = 1; off < 256; off <<= 1) {
        int t = (tid >= off) ? s[tid - off] : 0;
        __syncthreads();
        s[tid] += t;
        __syncthreads();
    }
    if (i < n) row_ptr[i] = s[tid] - v;
    if (tid == 255) bsum[blockIdx.x] = s[255];
}

// single-block exclusive scan of bsum (any nb, carry loop)
__global__ void k_scan_bsum(int* __restrict__ bsum, int nb) {
    __shared__ int s[256];
    __shared__ int carry;
    int tid = threadIdx.x;
    if (tid == 0) carry = 0;
    __syncthreads();
    for (int start = 0; start < nb; start += 256) {
        int i = start + tid;
        int v = (i < nb) ? bsum[i] : 0;
        s[tid] = v;
        __syncthreads();
#pragma unroll
        for (int off = 1; off < 256; off <<= 1) {
            int t = (tid >= off) ? s[tid - off] : 0;
            __syncthreads();
            s[tid] += t;
            __syncthreads();
        }
        if (i < nb) bsum[i] = s[tid] - v + carry;
        __syncthreads();
        if (tid == 0) carry += s[255];
        __syncthreads();
    }
}

__global__ void k_finalize(const int* __restrict__ cnt_out, const int* __restrict__ cnt_in,
                           const int* __restrict__ bsum,
                           int* __restrict__ row_ptr, int* __restrict__ cursor,
                           float* __restrict__ norm_src, float* __restrict__ norm_dst, int n) {
    int i = blockIdx.x * blockDim.x + threadIdx.x;
    if (i >= n) return;
    int rp = row_ptr[i] + bsum[i >> 8];
    row_ptr[i] = rp;
    cursor[i] = rp;
    norm_src[i] = rsqrtf((float)(cnt_out[i] + 1));  // +1 self loop
    norm_dst[i] = rsqrtf((float)(cnt_in[i] + 1));
}

__global__ void k_bin(const int* __restrict__ src, const int* __restrict__ dst,
                      int* __restrict__ cursor, int* __restrict__ col, int e) {
    int i = blockIdx.x * blockDim.x + threadIdx.x;
    if (i < e) {
        int p = atomicAdd(&cursor[dst[i]], 1);
        col[p] = src[i];
    }
}

// fused gather + MLP: one wave per node (grid-stride), weights staged in LDS once/block
__global__ void k_node(const float* __restrict__ x,
                       const int* __restrict__ row_ptr, const int* __restrict__ cnt_in,
                       const int* __restrict__ col,
                       const float* __restrict__ norm_src, const float* __restrict__ norm_dst,
                       const float* __restrict__ W1, const float* __restrict__ b1,
                       const float* __restrict__ W2,
                       float* __restrict__ zs, int n) {
    __shared__ float sW1[D * D];
    __shared__ float sb1[D];
    __shared__ float sW2[D];
    __shared__ float sa[4][D];
    int tid = threadIdx.x;
    for (int k = tid; k < D * D; k += 256) sW1[k] = W1[k];
    if (tid < D) { sb1[tid] = b1[tid]; sW2[tid] = W2[tid]; }
    __syncthreads();

    int wave = tid >> 6;
    int lane = tid & 63;
    int nwaves = gridDim.x * 4;

    for (int node = blockIdx.x * 4 + wave; node < n; node += nwaves) {
        int base = row_ptr[node];
        int cnt = cnt_in[node];
        // self-loop + neighbor gather
        float acc = norm_src[node] * x[(size_t)node * D + lane];
        for (int j = 0; j < cnt; ++j) {
            int s = col[base + j];
            acc += norm_src[s] * x[(size_t)s * D + lane];
        }
        acc *= norm_dst[node];

        sa[wave][lane] = acc;   // same-wave LDS exchange, no barrier needed
        float h = sb1[lane];
#pragma unroll
        for (int k = 0; k < D; ++k)
            h += sa[wave][k] * sW1[k * D + lane];
        h = fmaxf(h, 0.0f);

        float zp = h * sW2[lane];
#pragma unroll
        for (int off = 32; off > 0; off >>= 1) zp += __shfl_down(zp, off);

        if (lane == 0) zs[node] = zp * norm_src[node];  // pre-scaled for layer-2
    }
}

// layer-2 gather: one thread per node
__global__ void k_out(const float* __restrict__ zs,
                      const int* __restrict__ row_ptr, const int* __restrict__ cnt_in,
                      const int* __restrict__ col,
                      const float* __restrict__ norm_dst, const float* __restrict__ b2,
                      float* __restrict__ out, int n) {
    int i = blockIdx.x * blockDim.x + threadIdx.x;
    if (i >= n) return;
    float s = zs[i];  // self loop (already norm_src-scaled)
    int base = row_ptr[i];
    int c = cnt_in[i];
    for (int j = 0; j < c; ++j) s += zs[col[base + j]];
    out[i] = norm_dst[i] * s + b2[0];
}

extern "C" void kernel_launch(void* const* d_in, const int* in_sizes, int n_in,
                              void* d_out, int out_size, void* d_ws, size_t ws_size,
                              hipStream_t stream) {
    const float* x  = (const float*)d_in[0];
    const int*   ei = (const int*)d_in[1];
    const float* W1 = (const float*)d_in[2];
    const float* b1 = (const float*)d_in[3];
    const float* W2 = (const float*)d_in[4];
    const float* b2 = (const float*)d_in[5];
    float* out = (float*)d_out;

    const int n = in_sizes[0] / D;   // 50000
    const int e = in_sizes[1] / 2;   // 800000
    const int* src = ei;
    const int* dst = ei + e;

    const int nb = (n + 255) / 256;  // scan blocks

    // workspace layout
    char* ws = (char*)d_ws;
    int*   cnt_out  = (int*)ws;                 ws += sizeof(int) * (size_t)n;
    int*   cnt_in   = (int*)ws;                 ws += sizeof(int) * (size_t)n;
    int*   row_ptr  = (int*)ws;                 ws += sizeof(int) * (size_t)n;
    int*   cursor   = (int*)ws;                 ws += sizeof(int) * (size_t)n;
    int*   bsum     = (int*)ws;                 ws += sizeof(int) * (size_t)((nb + 255) & ~255);
    float* norm_src = (float*)ws;               ws += sizeof(float) * (size_t)n;
    float* norm_dst = (float*)ws;               ws += sizeof(float) * (size_t)n;
    float* zs       = (float*)ws;               ws += sizeof(float) * (size_t)n;
    int*   col      = (int*)ws;                 ws += sizeof(int) * (size_t)e;

    const int B = 256;

    k_zero<<<(n + B - 1) / B, B, 0, stream>>>(cnt_out, cnt_in, n);
    k_hist<<<(e + B - 1) / B, B, 0, stream>>>(src, dst, cnt_out, cnt_in, e);
    k_scan_block<<<nb, 256, 0, stream>>>(cnt_in, row_ptr, bsum, n);
    k_scan_bsum<<<1, 256, 0, stream>>>(bsum, nb);
    k_finalize<<<(n + B - 1) / B, B, 0, stream>>>(cnt_out, cnt_in, bsum, row_ptr, cursor,
                                                  norm_src, norm_dst, n);
    k_bin<<<(e + B - 1) / B, B, 0, stream>>>(src, dst, cursor, col, e);
    k_node<<<2048, 256, 0, stream>>>(x, row_ptr, cnt_in, col, norm_src, norm_dst,
                                     W1, b1, W2, zs, n);
    k_out<<<(n + B - 1) / B, B, 0, stream>>>(zs, row_ptr, cnt_in, col, norm_dst, b2, out, n);
}

// Round 3
// 206.728 us; speedup vs baseline: 1.6955x; 1.3504x over previous
//
#include <hip/hip_runtime.h>

// GCN forward, f32, CSR-gather with batched-index latency hiding.
// Pipeline:
//  K1 zero counters
//  K2 edge histogram (int atomics)
//  K3/K4 two-level exclusive scan -> row_ptr
//  K5 finalize row_ptr/cursor/norms
//  K6 bin edges by dst
//  K7 fused per-node (1 wave/node): batched gather + MLP -> zs
//  K8 layer-2 gather -> out

constexpr int D = 64;

__global__ void k_zero(int* __restrict__ cnt_out, int* __restrict__ cnt_in, int n) {
    int i = blockIdx.x * blockDim.x + threadIdx.x;
    if (i < n) { cnt_out[i] = 0; cnt_in[i] = 0; }
}

__global__ void k_hist(const int* __restrict__ src, const int* __restrict__ dst,
                       int* __restrict__ cnt_out, int* __restrict__ cnt_in, int e) {
    int i = blockIdx.x * blockDim.x + threadIdx.x;
    if (i < e) {
        atomicAdd(&cnt_out[src[i]], 1);
        atomicAdd(&cnt_in[dst[i]], 1);
    }
}

__global__ void k_scan_block(const int* __restrict__ cnt_in, int* __restrict__ row_ptr,
                             int* __restrict__ bsum, int n) {
    __shared__ int s[256];
    int tid = threadIdx.x;
    int i = blockIdx.x * 256 + tid;
    int v = (i < n) ? cnt_in[i] : 0;
    s[tid] = v;
    __syncthreads();
#pragma unroll
    for (int off = 1; off < 256; off <<= 1) {
        int t = (tid >= off) ? s[tid - off] : 0;
        __syncthreads();
        s[tid] += t;
        __syncthreads();
    }
    if (i < n) row_ptr[i] = s[tid] - v;
    if (tid == 255) bsum[blockIdx.x] = s[255];
}

__global__ void k_scan_bsum(int* __restrict__ bsum, int nb) {
    __shared__ int s[256];
    __shared__ int carry;
    int tid = threadIdx.x;
    if (tid == 0) carry = 0;
    __syncthreads();
    for (int start = 0; start < nb; start += 256) {
        int i = start + tid;
        int v = (i < nb) ? bsum[i] : 0;
        s[tid] = v;
        __syncthreads();
#pragma unroll
        for (int off = 1; off < 256; off <<= 1) {
            int t = (tid >= off) ? s[tid - off] : 0;
            __syncthreads();
            s[tid] += t;
            __syncthreads();
        }
        if (i < nb) bsum[i] = s[tid] - v + carry;
        __syncthreads();
        if (tid == 0) carry += s[255];
        __syncthreads();
    }
}

__global__ void k_finalize(const int* __restrict__ cnt_out, const int* __restrict__ cnt_in,
                           const int* __restrict__ bsum,
                           int* __restrict__ row_ptr, int* __restrict__ cursor,
                           float* __restrict__ norm_src, float* __restrict__ norm_dst, int n) {
    int i = blockIdx.x * blockDim.x + threadIdx.x;
    if (i >= n) return;
    int rp = row_ptr[i] + bsum[i >> 8];
    row_ptr[i] = rp;
    cursor[i] = rp;
    norm_src[i] = rsqrtf((float)(cnt_out[i] + 1));
    norm_dst[i] = rsqrtf((float)(cnt_in[i] + 1));
}

__global__ void k_bin(const int* __restrict__ src, const int* __restrict__ dst,
                      int* __restrict__ cursor, int* __restrict__ col, int e) {
    int i = blockIdx.x * blockDim.x + threadIdx.x;
    if (i < e) {
        int p = atomicAdd(&cursor[dst[i]], 1);
        col[p] = src[i];
    }
}

// one wave per node; batched index gather + 4x-unrolled feature gather
__global__ void __launch_bounds__(256) k_node(
        const float* __restrict__ x,
        const int* __restrict__ row_ptr, const int* __restrict__ cnt_in,
        const int* __restrict__ col,
        const float* __restrict__ norm_src, const float* __restrict__ norm_dst,
        const float* __restrict__ W1, const float* __restrict__ b1,
        const float* __restrict__ W2,
        float* __restrict__ zs, int n) {
    __shared__ float sW1[D * D];
    __shared__ float sb1[D];
    __shared__ float sW2[D];
    __shared__ float sa[4][D];
    int tid = threadIdx.x;
    for (int k = tid; k < D * D; k += 256) sW1[k] = W1[k];
    if (tid < D) { sb1[tid] = b1[tid]; sW2[tid] = W2[tid]; }
    __syncthreads();

    int wave = tid >> 6;
    int lane = tid & 63;
    int node = blockIdx.x * 4 + wave;
    if (node >= n) return;   // no __syncthreads below

    int base = row_ptr[node];
    int cnt = cnt_in[node];
    float acc = norm_src[node] * x[(size_t)node * D + lane];  // self loop

    for (int b0 = 0; b0 < cnt; b0 += 64) {
        int m = cnt - b0; if (m > 64) m = 64;
        // lanes cooperatively fetch indices + weights for this batch
        int   idx = (lane < m) ? col[base + b0 + lane] : 0;
        float nsw = (lane < m) ? norm_src[idx] : 0.0f;
        int j = 0;
        for (; j + 4 <= m; j += 4) {
            int   s0 = __shfl(idx, j),     s1 = __shfl(idx, j + 1);
            int   s2 = __shfl(idx, j + 2), s3 = __shfl(idx, j + 3);
            float w0 = __shfl(nsw, j),     w1 = __shfl(nsw, j + 1);
            float w2 = __shfl(nsw, j + 2), w3 = __shfl(nsw, j + 3);
            float x0 = x[(size_t)s0 * D + lane];
            float x1 = x[(size_t)s1 * D + lane];
            float x2 = x[(size_t)s2 * D + lane];
            float x3 = x[(size_t)s3 * D + lane];
            acc += w0 * x0;
            acc += w1 * x1;
            acc += w2 * x2;
            acc += w3 * x3;
        }
        for (; j < m; ++j) {
            int   s0 = __shfl(idx, j);
            float w0 = __shfl(nsw, j);
            acc += w0 * x[(size_t)s0 * D + lane];
        }
    }
    acc *= norm_dst[node];

    sa[wave][lane] = acc;   // same-wave LDS exchange (in-order DS, no barrier)
    float h = sb1[lane];
#pragma unroll
    for (int k = 0; k < D; ++k)
        h += sa[wave][k] * sW1[k * D + lane];
    h = fmaxf(h, 0.0f);

    float zp = h * sW2[lane];
#pragma unroll
    for (int off = 32; off > 0; off >>= 1) zp += __shfl_down(zp, off);

    if (lane == 0) zs[node] = zp * norm_src[node];  // pre-scaled for layer 2
}

__global__ void k_out(const float* __restrict__ zs,
                      const int* __restrict__ row_ptr, const int* __restrict__ cnt_in,
                      const int* __restrict__ col,
                      const float* __restrict__ norm_dst, const float* __restrict__ b2,
                      float* __restrict__ out, int n) {
    int i = blockIdx.x * blockDim.x + threadIdx.x;
    if (i >= n) return;
    float s = zs[i];
    int base = row_ptr[i];
    int c = cnt_in[i];
    int j = 0;
    for (; j + 4 <= c; j += 4) {
        float a0 = zs[col[base + j]];
        float a1 = zs[col[base + j + 1]];
        float a2 = zs[col[base + j + 2]];
        float a3 = zs[col[base + j + 3]];
        s += a0 + a1 + a2 + a3;
    }
    for (; j < c; ++j) s += zs[col[base + j]];
    out[i] = norm_dst[i] * s + b2[0];
}

extern "C" void kernel_launch(void* const* d_in, const int* in_sizes, int n_in,
                              void* d_out, int out_size, void* d_ws, size_t ws_size,
                              hipStream_t stream) {
    const float* x  = (const float*)d_in[0];
    const int*   ei = (const int*)d_in[1];
    const float* W1 = (const float*)d_in[2];
    const float* b1 = (const float*)d_in[3];
    const float* W2 = (const float*)d_in[4];
    const float* b2 = (const float*)d_in[5];
    float* out = (float*)d_out;

    const int n = in_sizes[0] / D;   // 50000
    const int e = in_sizes[1] / 2;   // 800000
    const int* src = ei;
    const int* dst = ei + e;

    const int nb = (n + 255) / 256;

    char* ws = (char*)d_ws;
    int*   cnt_out  = (int*)ws;   ws += sizeof(int) * (size_t)n;
    int*   cnt_in   = (int*)ws;   ws += sizeof(int) * (size_t)n;
    int*   row_ptr  = (int*)ws;   ws += sizeof(int) * (size_t)n;
    int*   cursor   = (int*)ws;   ws += sizeof(int) * (size_t)n;
    int*   bsum     = (int*)ws;   ws += sizeof(int) * (size_t)((nb + 255) & ~255);
    float* norm_src = (float*)ws; ws += sizeof(float) * (size_t)n;
    float* norm_dst = (float*)ws; ws += sizeof(float) * (size_t)n;
    float* zs       = (float*)ws; ws += sizeof(float) * (size_t)n;
    int*   col      = (int*)ws;   ws += sizeof(int) * (size_t)e;

    const int B = 256;

    k_zero<<<(n + B - 1) / B, B, 0, stream>>>(cnt_out, cnt_in, n);
    k_hist<<<(e + B - 1) / B, B, 0, stream>>>(src, dst, cnt_out, cnt_in, e);
    k_scan_block<<<nb, 256, 0, stream>>>(cnt_in, row_ptr, bsum, n);
    k_scan_bsum<<<1, 256, 0, stream>>>(bsum, nb);
    k_finalize<<<(n + B - 1) / B, B, 0, stream>>>(cnt_out, cnt_in, bsum, row_ptr, cursor,
                                                  norm_src, norm_dst, n);
    k_bin<<<(e + B - 1) / B, B, 0, stream>>>(src, dst, cursor, col, e);
    k_node<<<(n + 3) / 4, 256, 0, stream>>>(x, row_ptr, cnt_in, col, norm_src, norm_dst,
                                            W1, b1, W2, zs, n);
    k_out<<<(n + B - 1) / B, B, 0, stream>>>(zs, row_ptr, cnt_in, col, norm_dst, b2, out, n);
}

// Round 4
// 204.285 us; speedup vs baseline: 1.7157x; 1.0120x over previous
//
#include <hip/hip_runtime.h>

// GCN forward, f32, CSR-gather; MLP fully in registers (readlane broadcast).
// Pipeline:
//  K1 zero counters
//  K2 edge histogram (int atomics)
//  K3/K4 two-level exclusive scan -> row_ptr
//  K5 finalize row_ptr/cursor/norms
//  K6 bin edges by dst
//  K7 fused per-node (1 wave/node, grid-stride): gather + reg-MLP -> zs
//  K8 layer-2 gather (4 lanes/node) -> out

constexpr int D = 64;

__device__ __forceinline__ int rl_i(int v, int l) {
    return __builtin_amdgcn_readlane(v, l);
}
__device__ __forceinline__ float rl_f(float v, int l) {
    return __builtin_bit_cast(float, __builtin_amdgcn_readlane(__builtin_bit_cast(int, v), l));
}

__global__ void k_zero(int* __restrict__ cnt_out, int* __restrict__ cnt_in, int n) {
    int i = blockIdx.x * blockDim.x + threadIdx.x;
    if (i < n) { cnt_out[i] = 0; cnt_in[i] = 0; }
}

__global__ void k_hist(const int* __restrict__ src, const int* __restrict__ dst,
                       int* __restrict__ cnt_out, int* __restrict__ cnt_in, int e) {
    int i = blockIdx.x * blockDim.x + threadIdx.x;
    if (i < e) {
        atomicAdd(&cnt_out[src[i]], 1);
        atomicAdd(&cnt_in[dst[i]], 1);
    }
}

__global__ void k_scan_block(const int* __restrict__ cnt_in, int* __restrict__ row_ptr,
                             int* __restrict__ bsum, int n) {
    __shared__ int s[256];
    int tid = threadIdx.x;
    int i = blockIdx.x * 256 + tid;
    int v = (i < n) ? cnt_in[i] : 0;
    s[tid] = v;
    __syncthreads();
#pragma unroll
    for (int off = 1; off < 256; off <<= 1) {
        int t = (tid >= off) ? s[tid - off] : 0;
        __syncthreads();
        s[tid] += t;
        __syncthreads();
    }
    if (i < n) row_ptr[i] = s[tid] - v;
    if (tid == 255) bsum[blockIdx.x] = s[255];
}

__global__ void k_scan_bsum(int* __restrict__ bsum, int nb) {
    __shared__ int s[256];
    __shared__ int carry;
    int tid = threadIdx.x;
    if (tid == 0) carry = 0;
    __syncthreads();
    for (int start = 0; start < nb; start += 256) {
        int i = start + tid;
        int v = (i < nb) ? bsum[i] : 0;
        s[tid] = v;
        __syncthreads();
#pragma unroll
        for (int off = 1; off < 256; off <<= 1) {
            int t = (tid >= off) ? s[tid - off] : 0;
            __syncthreads();
            s[tid] += t;
            __syncthreads();
        }
        if (i < nb) bsum[i] = s[tid] - v + carry;
        __syncthreads();
        if (tid == 0) carry += s[255];
        __syncthreads();
    }
}

__global__ void k_finalize(const int* __restrict__ cnt_out, const int* __restrict__ cnt_in,
                           const int* __restrict__ bsum,
                           int* __restrict__ row_ptr, int* __restrict__ cursor,
                           float* __restrict__ norm_src, float* __restrict__ norm_dst, int n) {
    int i = blockIdx.x * blockDim.x + threadIdx.x;
    if (i >= n) return;
    int rp = row_ptr[i] + bsum[i >> 8];
    row_ptr[i] = rp;
    cursor[i] = rp;
    norm_src[i] = rsqrtf((float)(cnt_out[i] + 1));
    norm_dst[i] = rsqrtf((float)(cnt_in[i] + 1));
}

__global__ void k_bin(const int* __restrict__ src, const int* __restrict__ dst,
                      int* __restrict__ cursor, int* __restrict__ col, int e) {
    int i = blockIdx.x * blockDim.x + threadIdx.x;
    if (i < e) {
        int p = atomicAdd(&cursor[dst[i]], 1);
        col[p] = src[i];
    }
}

// one wave per node (grid-stride); W1 column + b1 + W2 in registers;
// all cross-lane traffic via v_readlane (no LDS at all)
__global__ void __launch_bounds__(256, 4) k_node(
        const float* __restrict__ x,
        const int* __restrict__ row_ptr, const int* __restrict__ cnt_in,
        const int* __restrict__ col,
        const float* __restrict__ norm_src, const float* __restrict__ norm_dst,
        const float* __restrict__ W1, const float* __restrict__ b1,
        const float* __restrict__ W2,
        float* __restrict__ zs, int n) {
    int tid = threadIdx.x;
    int wave = tid >> 6;
    int lane = tid & 63;

    // per-wave register copies of the weights (amortized over grid-stride nodes)
    float w1[D];
#pragma unroll
    for (int k = 0; k < D; ++k) w1[k] = W1[k * D + lane];
    float b1v = b1[lane];
    float w2v = W2[lane];

    int nwaves = gridDim.x * 4;
    for (int node = blockIdx.x * 4 + wave; node < n; node += nwaves) {
        int base = row_ptr[node];
        int cnt = cnt_in[node];
        float acc = norm_src[node] * x[(size_t)node * D + lane];  // self loop

        for (int b0 = 0; b0 < cnt; b0 += 64) {
            int m = cnt - b0; if (m > 64) m = 64;
            int   idx = (lane < m) ? col[base + b0 + lane] : 0;
            float nsw = (lane < m) ? norm_src[idx] : 0.0f;
            int j = 0;
            for (; j + 8 <= m; j += 8) {
                int s0 = rl_i(idx, j + 0), s1 = rl_i(idx, j + 1);
                int s2 = rl_i(idx, j + 2), s3 = rl_i(idx, j + 3);
                int s4 = rl_i(idx, j + 4), s5 = rl_i(idx, j + 5);
                int s6 = rl_i(idx, j + 6), s7 = rl_i(idx, j + 7);
                float x0 = x[(size_t)s0 * D + lane];
                float x1 = x[(size_t)s1 * D + lane];
                float x2 = x[(size_t)s2 * D + lane];
                float x3 = x[(size_t)s3 * D + lane];
                float x4 = x[(size_t)s4 * D + lane];
                float x5 = x[(size_t)s5 * D + lane];
                float x6 = x[(size_t)s6 * D + lane];
                float x7 = x[(size_t)s7 * D + lane];
                acc = fmaf(rl_f(nsw, j + 0), x0, acc);
                acc = fmaf(rl_f(nsw, j + 1), x1, acc);
                acc = fmaf(rl_f(nsw, j + 2), x2, acc);
                acc = fmaf(rl_f(nsw, j + 3), x3, acc);
                acc = fmaf(rl_f(nsw, j + 4), x4, acc);
                acc = fmaf(rl_f(nsw, j + 5), x5, acc);
                acc = fmaf(rl_f(nsw, j + 6), x6, acc);
                acc = fmaf(rl_f(nsw, j + 7), x7, acc);
            }
            for (; j < m; ++j) {
                acc = fmaf(rl_f(nsw, j), x[(size_t)rl_i(idx, j) * D + lane], acc);
            }
        }
        acc *= norm_dst[node];

        // dense 64x64 transform, fully in registers: h[lane] = b1 + sum_k a[k]*W1[k][lane]
        float h = b1v;
#pragma unroll
        for (int k = 0; k < D; ++k)
            h = fmaf(rl_f(acc, k), w1[k], h);
        h = fmaxf(h, 0.0f);

        float zp = h * w2v;
#pragma unroll
        for (int off = 32; off > 0; off >>= 1) zp += __shfl_down(zp, off);

        if (lane == 0) zs[node] = zp * norm_src[node];  // pre-scaled for layer 2
    }
}

// layer-2 gather: 4 lanes per node
__global__ void k_out(const float* __restrict__ zs,
                      const int* __restrict__ row_ptr, const int* __restrict__ cnt_in,
                      const int* __restrict__ col,
                      const float* __restrict__ norm_dst, const float* __restrict__ b2,
                      float* __restrict__ out, int n) {
    int g = blockIdx.x * blockDim.x + threadIdx.x;
    int node = g >> 2;
    int sub = g & 3;
    if (node >= n) return;
    int base = row_ptr[node];
    int c = cnt_in[node];
    float s = (sub == 0) ? zs[node] : 0.0f;  // self loop
    for (int j = sub; j < c; j += 4) s += zs[col[base + j]];
    s += __shfl_xor(s, 1);
    s += __shfl_xor(s, 2);
    if (sub == 0) out[node] = norm_dst[node] * s + b2[0];
}

extern "C" void kernel_launch(void* const* d_in, const int* in_sizes, int n_in,
                              void* d_out, int out_size, void* d_ws, size_t ws_size,
                              hipStream_t stream) {
    const float* x  = (const float*)d_in[0];
    const int*   ei = (const int*)d_in[1];
    const float* W1 = (const float*)d_in[2];
    const float* b1 = (const float*)d_in[3];
    const float* W2 = (const float*)d_in[4];
    const float* b2 = (const float*)d_in[5];
    float* out = (float*)d_out;

    const int n = in_sizes[0] / D;   // 50000
    const int e = in_sizes[1] / 2;   // 800000
    const int* src = ei;
    const int* dst = ei + e;

    const int nb = (n + 255) / 256;

    char* ws = (char*)d_ws;
    int*   cnt_out  = (int*)ws;   ws += sizeof(int) * (size_t)n;
    int*   cnt_in   = (int*)ws;   ws += sizeof(int) * (size_t)n;
    int*   row_ptr  = (int*)ws;   ws += sizeof(int) * (size_t)n;
    int*   cursor   = (int*)ws;   ws += sizeof(int) * (size_t)n;
    int*   bsum     = (int*)ws;   ws += sizeof(int) * (size_t)((nb + 255) & ~255);
    float* norm_src = (float*)ws; ws += sizeof(float) * (size_t)n;
    float* norm_dst = (float*)ws; ws += sizeof(float) * (size_t)n;
    float* zs       = (float*)ws; ws += sizeof(float) * (size_t)n;
    int*   col      = (int*)ws;   ws += sizeof(int) * (size_t)e;

    const int B = 256;

    k_zero<<<(n + B - 1) / B, B, 0, stream>>>(cnt_out, cnt_in, n);
    k_hist<<<(e + B - 1) / B, B, 0, stream>>>(src, dst, cnt_out, cnt_in, e);
    k_scan_block<<<nb, 256, 0, stream>>>(cnt_in, row_ptr, bsum, n);
    k_scan_bsum<<<1, 256, 0, stream>>>(bsum, nb);
    k_finalize<<<(n + B - 1) / B, B, 0, stream>>>(cnt_out, cnt_in, bsum, row_ptr, cursor,
                                                  norm_src, norm_dst, n);
    k_bin<<<(e + B - 1) / B, B, 0, stream>>>(src, dst, cursor, col, e);
    k_node<<<2560, 256, 0, stream>>>(x, row_ptr, cnt_in, col, norm_src, norm_dst,
                                     W1, b1, W2, zs, n);
    k_out<<<((size_t)n * 4 + B - 1) / B, B, 0, stream>>>(zs, row_ptr, cnt_in, col,
                                                         norm_dst, b2, out, n);
}